// Round 11
// baseline (73.893 us; speedup 1.0000x reference)
//
#include <hip/hip_runtime.h>
#include <math.h>

#define DD  64
#define WPB 4    // waves per 256-thread block, one batch row per wave

typedef float v2f __attribute__((ext_vector_type(2)));

// Packed fp32 FMA (VOP3P): 2 MACs/instr, the r9 win (24 -> 20.4 us kernel).
__device__ __forceinline__ v2f pk_fma(v2f a, v2f b, v2f c) {
    v2f d;
    asm("v_pk_fma_f32 %0, %1, %2, %3" : "=v"(d) : "v"(a), "v"(b), "v"(c));
    return d;
}

// tanh(a) = 1 - 2/(e+1), e = exp2(a*2*log2(e)); 5 VALU instrs, no clamp
// needed (|zl| <= ~13 << 44 overflow).
__device__ __forceinline__ float fast_tanh(float a) {
    const float e = __builtin_amdgcn_exp2f(a * 2.885390081777927f);
    return fmaf(-2.0f, __builtin_amdgcn_rcpf(e + 1.0f), 1.0f);
}

// zl = xi + dot(w, z): 16 ds_read_b128 (same-address bcast, conflict-free)
// + 32 v_pk_fma_f32. Best measured structure (r9).
__device__ __forceinline__ float matvec_pk(const v2f* __restrict__ w2,
                                           const float* zs, float xi) {
    const float4* zs4 = reinterpret_cast<const float4*>(zs);
    v2f a0 = {xi, 0.0f}, a1 = {0.0f, 0.0f}, a2 = {0.0f, 0.0f}, a3 = {0.0f, 0.0f};
#pragma unroll
    for (int q = 0; q < 16; q += 2) {
        const float4 p = zs4[q];
        const float4 r = zs4[q + 1];
        a0 = pk_fma(w2[2 * q],     (v2f){p.x, p.y}, a0);
        a1 = pk_fma(w2[2 * q + 1], (v2f){p.z, p.w}, a1);
        a2 = pk_fma(w2[2 * q + 2], (v2f){r.x, r.y}, a2);
        a3 = pk_fma(w2[2 * q + 3], (v2f){r.z, r.w}, a3);
    }
    const v2f s = (a0 + a1) + (a2 + a3);
    return s.x + s.y;
}

// One Picard apply G(z) = tanh(W z + x); single-wave lockstep, wave_barrier
// is a compiler ordering fence only.
__device__ __forceinline__ float apply_G(const v2f* __restrict__ w2, float* zs,
                                         float xi, float z, int lane) {
    zs[lane] = z;
    __builtin_amdgcn_wave_barrier();
    const float zl = matvec_pk(w2, zs, xi);
    __builtin_amdgcn_wave_barrier();
    return fast_tanh(zl);
}

// One wave per batch row; lane i owns element i and W row i in registers.
// N-REDUCTION via per-element Aitken delta-squared: rounds 1-10 showed the
// per-apply cost is ~incompressible (~20us kernel = N_applies x ~60 instrs);
// Aitken annihilates the dominant error eigenmode with NO cross-lane work
// (r3's Anderson lost to its 3 shuffle-reduction trees/iter). Guard
// |corr|<=4|d2| falls back to plain Picard (NaN-safe: NaN<= compares false).
// Exit test is on a PLAIN apply's step (= true residual): a wave can only
// exit with residual < tol, so the 1e-4 zeroing epilogue cannot misfire.
// Tol 8e-6: exit 2-norm <= 6.4e-5 < 1e-4 (1.56x margin incl. eval noise).
__global__ __launch_bounds__(64 * WPB)
void tanh_fixed_point(const float* __restrict__ x,
                      const float* __restrict__ W,
                      float* __restrict__ out)
{
    __shared__ alignas(16) float zsh[WPB][DD];
    const int lane = threadIdx.x & 63;
    const int wid  = threadIdx.x >> 6;
    const int b    = blockIdx.x * WPB + wid;
    float* zs = zsh[wid];

    v2f w2[DD / 2];
#pragma unroll
    for (int j = 0; j < DD; j += 4) {
        const float4 v = *reinterpret_cast<const float4*>(W + lane * DD + j);
        w2[j / 2]     = (v2f){v.x, v.y};
        w2[j / 2 + 1] = (v2f){v.z, v.w};
    }

    const float xi = x[b * DD + lane];
    float z = fast_tanh(xi);            // z0 = tanh(x), as reference

    for (int grp = 0; grp < 16; ++grp) {       // cap 48 applies
        const float z1 = apply_G(w2, zs, xi, z,  lane);
        const float z2 = apply_G(w2, zs, xi, z1, lane);
        // Aitken: z* = z2 - d2^2/(d2-d1), per element, no reductions.
        const float d1 = z1 - z;
        const float d2 = z2 - z1;
        const float corr = d2 * d2 * __builtin_amdgcn_rcpf(d2 - d1);
        const bool ok = fabsf(corr) <= 4.0f * fabsf(d2);   // NaN -> false
        const float za = ok ? z2 - corr : z2;
        // Polish apply; its step IS the residual -> safe exit test.
        const float z3 = apply_G(w2, zs, xi, za, lane);
        const bool conv = fabsf(z3 - za) < 8e-6f;
        z = z3;
        if (__all(conv)) break;         // wave-uniform
    }

    // Mirror reference: zero rows with ||z - tanh(zW^T+x)||_2 > 1e-4.
    const float g = z - apply_G(w2, zs, xi, z, lane);
    float s = g * g;
#pragma unroll
    for (int off = 32; off; off >>= 1)
        s += __shfl_xor(s, off);
    if (s > 1e-8f) z = 0.0f;

    out[b * DD + lane] = z;
}

extern "C" void kernel_launch(void* const* d_in, const int* in_sizes, int n_in,
                              void* d_out, int out_size, void* d_ws, size_t ws_size,
                              hipStream_t stream)
{
    const float* x = (const float*)d_in[0];   // [B, 64] fp32
    const float* W = (const float*)d_in[1];   // [64, 64] fp32
    float* out     = (float*)d_out;           // [B, 64] fp32
    const int B = in_sizes[0] / DD;           // 4096
    tanh_fixed_point<<<B / WPB, 64 * WPB, 0, stream>>>(x, W, out);
}